// Round 6
// baseline (82.882 us; speedup 1.0000x reference)
//
#include <hip/hip_runtime.h>

#define HID 1024
#define BATCH 256
#define KTASK 4096
#define TPB 4               // tasks per block
#define NCOL 32             // TPB*8 output cols = LDS rows
#define WSTRIDE 2064        // LDS row stride bytes (2048 data + 16 pad, 16B-aligned)

typedef __bf16 bf16x8 __attribute__((ext_vector_type(8)));
typedef __bf16 bf16x4 __attribute__((ext_vector_type(4)));
typedef float f32x4 __attribute__((ext_vector_type(4)));

__global__ __launch_bounds__(256, 4)
void cvt_emb_kernel(const float* __restrict__ emb, __bf16* __restrict__ dst) {
    int i = (blockIdx.x * 256 + threadIdx.x) * 4;
    float4 v = *(const float4*)(emb + i);
    bf16x4 r;
    r[0] = (__bf16)v.x; r[1] = (__bf16)v.y; r[2] = (__bf16)v.z; r[3] = (__bf16)v.w;
    *(bf16x4*)(dst + i) = r;
}

// Phase 1: stream the block's 4 gathered W1 heads (128 KB fp32) contiguously,
// cvt to bf16, park ALL of it in LDS. Phase 2: barrier-free MFMA k-loop
// (B from LDS, A from L2-resident bf16 emb). 2 blocks/CU: one stages (HBM)
// while the other computes (LDS/MFMA).
__global__ __launch_bounds__(512, 4)
void mtc_kernel(const __bf16* __restrict__ embb, const float* __restrict__ W1,
                const float* __restrict__ b1, const float* __restrict__ W2,
                const float* __restrict__ b2, const int* __restrict__ tids,
                float* __restrict__ out)
{
    __shared__ __align__(16) char wlds[NCOL * WSTRIDE];   // 64.5 KB

    const int t = threadIdx.x;
    const int lane = t & 63;
    const int w = t >> 6;                // 0..7
    const int blk = blockIdx.x;          // 0..1023

    int tk[TPB];
#pragma unroll
    for (int i = 0; i < TPB; ++i) tk[i] = tids[blk * TPB + i];

    // ---------------- Phase 1: contiguous W1 gather -> LDS ----------------
    // flat float4 index f = t + j*512 over 8192 float4 (4 tasks * 2048 each).
    // Per wave-instruction: 64 lanes * 16B = 1 KB contiguous within one task.
    {
        float4 v[16];
#pragma unroll
        for (int j = 0; j < 16; ++j) {
            const int f = t + j * 512;
            const int tl = j >> 2;                       // task-local, uniform per j
            const float* p = W1 + (size_t)tk[tl] * (8 * HID) + (size_t)(f & 2047) * 4;
            v[j] = *(const float4*)p;
        }
#pragma unroll
        for (int j = 0; j < 16; ++j) {
            const int f = t + j * 512;
            const int row = f >> 8;                      // 0..31  (task*8 + o)
            const int q   = f & 255;                     // float4 index within row
            bf16x4 r;
            r[0] = (__bf16)v[j].x; r[1] = (__bf16)v[j].y;
            r[2] = (__bf16)v[j].z; r[3] = (__bf16)v[j].w;
            *(bf16x4*)(&wlds[0] + row * WSTRIDE + q * 8) = r;
        }
    }
    __syncthreads();

    // ---------------- Phase 2: barrier-free k-loop ----------------
    // Wave w: rows w*32 + mt*16 + (lane&15), mt=0,1; cols nt*16 + (lane&15), nt=0,1.
    const __bf16* agp = embb + (size_t)(w * 32 + (lane & 15)) * HID + (lane >> 4) * 8;
    const char* b0p = &wlds[0] + (lane & 15) * WSTRIDE + (lane >> 4) * 16;
    const char* b1p = b0p + 16 * WSTRIDE;

    f32x4 acc[2][2];
    const f32x4 zero = {0.f, 0.f, 0.f, 0.f};
#pragma unroll
    for (int i = 0; i < 2; ++i)
#pragma unroll
        for (int j = 0; j < 2; ++j) acc[i][j] = zero;

    bf16x8 aA0 = *(const bf16x8*)(agp);
    bf16x8 aA1 = *(const bf16x8*)(agp + 16 * HID);
    bf16x8 aB0 = *(const bf16x8*)(agp + 32);
    bf16x8 aB1 = *(const bf16x8*)(agp + 32 + 16 * HID);

#pragma unroll
    for (int s = 0; s < 32; s += 2) {
        {   // even step s: consume aA, then prefetch A(s+2) into aA
            bf16x8 bf0 = *(const bf16x8*)(b0p + s * 64);
            bf16x8 bf1 = *(const bf16x8*)(b1p + s * 64);
            acc[0][0] = __builtin_amdgcn_mfma_f32_16x16x32_bf16(aA0, bf0, acc[0][0], 0, 0, 0);
            acc[0][1] = __builtin_amdgcn_mfma_f32_16x16x32_bf16(aA0, bf1, acc[0][1], 0, 0, 0);
            acc[1][0] = __builtin_amdgcn_mfma_f32_16x16x32_bf16(aA1, bf0, acc[1][0], 0, 0, 0);
            acc[1][1] = __builtin_amdgcn_mfma_f32_16x16x32_bf16(aA1, bf1, acc[1][1], 0, 0, 0);
            if (s + 2 < 32) {
                aA0 = *(const bf16x8*)(agp + (s + 2) * 32);
                aA1 = *(const bf16x8*)(agp + (s + 2) * 32 + 16 * HID);
            }
        }
        {   // odd step s+1: consume aB, then prefetch A(s+3) into aB
            bf16x8 bf0 = *(const bf16x8*)(b0p + (s + 1) * 64);
            bf16x8 bf1 = *(const bf16x8*)(b1p + (s + 1) * 64);
            acc[0][0] = __builtin_amdgcn_mfma_f32_16x16x32_bf16(aB0, bf0, acc[0][0], 0, 0, 0);
            acc[0][1] = __builtin_amdgcn_mfma_f32_16x16x32_bf16(aB0, bf1, acc[0][1], 0, 0, 0);
            acc[1][0] = __builtin_amdgcn_mfma_f32_16x16x32_bf16(aB1, bf0, acc[1][0], 0, 0, 0);
            acc[1][1] = __builtin_amdgcn_mfma_f32_16x16x32_bf16(aB1, bf1, acc[1][1], 0, 0, 0);
            if (s + 3 < 32) {
                aB0 = *(const bf16x8*)(agp + (s + 3) * 32);
                aB1 = *(const bf16x8*)(agp + (s + 3) * 32 + 16 * HID);
            }
        }
    }

    // ---- epilogue: +b1, relu, *w2, shuffle-reduce over o (8 lanes), +b2, store
    const int col = lane & 15;
    const int rgrp = lane >> 4;
    const int o = col & 7;
#pragma unroll
    for (int nt = 0; nt < 2; ++nt) {
        const int tl = nt * 2 + (col >> 3);       // task-local 0..3
        const int task = tk[0];                   // placeholder; real select below
        const int task_r = (tl == 0) ? tk[0] : (tl == 1) ? tk[1] : (tl == 2) ? tk[2] : tk[3];
        (void)task;
        const float bb1 = b1[task_r * 8 + o];
        const float ww2 = W2[task_r * 8 + o];
#pragma unroll
        for (int mt = 0; mt < 2; ++mt) {
            float v[4];
#pragma unroll
            for (int r = 0; r < 4; ++r) {
                float x = acc[mt][nt][r] + bb1;
                x = x > 0.f ? x : 0.f;
                v[r] = x * ww2;
            }
#pragma unroll
            for (int m = 1; m <= 4; m <<= 1) {
#pragma unroll
                for (int r = 0; r < 4; ++r) v[r] += __shfl_xor(v[r], m, 64);
            }
            if ((lane & 7) == 0) {
                const float bb2 = b2[task_r];
                const int brow = w * 32 + mt * 16 + rgrp * 4;
                float4 o4 = make_float4(v[0] + bb2, v[1] + bb2, v[2] + bb2, v[3] + bb2);
                *(float4*)(out + (size_t)(blk * TPB + tl) * BATCH + brow) = o4;
            }
        }
    }
}

extern "C" void kernel_launch(void* const* d_in, const int* in_sizes, int n_in,
                              void* d_out, int out_size, void* d_ws, size_t ws_size,
                              hipStream_t stream) {
    const float* emb = (const float*)d_in[0];
    const float* W1  = (const float*)d_in[1];
    const float* b1  = (const float*)d_in[2];
    const float* W2  = (const float*)d_in[3];
    const float* b2  = (const float*)d_in[4];
    const int*   tid = (const int*)d_in[5];
    float* outp = (float*)d_out;
    __bf16* embb = (__bf16*)d_ws;   // 512 KB

    cvt_emb_kernel<<<dim3(BATCH * HID / (256 * 4)), dim3(256), 0, stream>>>(emb, embb);
    mtc_kernel<<<dim3(KTASK / TPB), dim3(512), 0, stream>>>(embb, W1, b1, W2, b2, tid, outp);
}

// Round 7
// 59.107 us; speedup vs baseline: 1.4022x; 1.4022x over previous
//
#include <hip/hip_runtime.h>

#define HID 1024
#define BATCH 256
#define KTASK 4096
#define TPB 8             // tasks per block
#define NCOL 64           // 8 tasks * 8 hidden units = LDS rows
#define KC 32             // k per step
#define STRIDE 80         // LDS row stride bytes (64 data + 16 pad)
#define BUFSZ (NCOL * STRIDE)

typedef __bf16 bf16x8 __attribute__((ext_vector_type(8)));
typedef __bf16 bf16x4 __attribute__((ext_vector_type(4)));
typedef float f32x4 __attribute__((ext_vector_type(4)));

static __device__ __forceinline__ bf16x4 cvt4(const float4& a) {
    bf16x4 r;
    r[0] = (__bf16)a.x; r[1] = (__bf16)a.y; r[2] = (__bf16)a.z; r[3] = (__bf16)a.w;
    return r;
}

__global__ __launch_bounds__(256, 4)
void cvt_emb_kernel(const float* __restrict__ emb, __bf16* __restrict__ dst) {
    int i = (blockIdx.x * 256 + threadIdx.x) * 4;
    float4 v = *(const float4*)(emb + i);
    *(bf16x4*)(dst + i) = cvt4(v);
}

// Quad-buffered k-loop with uniform 2-step load lead and NO vmcnt drain at
// barriers: step s issues A(s+2) and W(s+4), ds_writes W(s+2) (issued s-2),
// reads buffer (s&3) (ds_written at s-2, two barriers ago). Barrier = raw
// s_barrier + lgkmcnt(0) only -- HBM prefetch stays in flight across it.
__global__ __launch_bounds__(512, 4)
void mtc_kernel(const __bf16* __restrict__ embb, const float* __restrict__ W1,
                const float* __restrict__ b1, const float* __restrict__ W2,
                const float* __restrict__ b2, const int* __restrict__ tids,
                float* __restrict__ out)
{
    __shared__ __align__(16) char wbuf[4 * BUFSZ];   // 20.5 KB

    const int t = threadIdx.x;
    const int lane = t & 63;
    const int w = t >> 6;                // 0..7
    const int blk = blockIdx.x;          // task-group 0..511

    // ---- W1 staging: LDS row srow = (task tl, o); k-eighth sq (4 floats)
    const int srow = t >> 3;             // 0..63
    const int sq   = t & 7;              // 0..7
    const int stask = tids[blk * TPB + (srow >> 3)];
    const float* sgp = W1 + (size_t)stask * (8 * HID) + (size_t)(srow & 7) * HID + sq * 4;
    char* const swr = &wbuf[0] + srow * STRIDE + sq * 8;

    // ---- A fragments: wave w rows w*32 + bt*16 + (lane&15)
    const __bf16* agp = embb + (size_t)(w * 32 + (lane & 15)) * HID + (lane >> 4) * 8;
    const int boff = (lane & 15) * STRIDE + (lane >> 4) * 16;

    f32x4 acc[2][4];
    const f32x4 zero = {0.f, 0.f, 0.f, 0.f};
#pragma unroll
    for (int i = 0; i < 2; ++i)
#pragma unroll
        for (int j = 0; j < 4; ++j) acc[i][j] = zero;

    bf16x8 aS[4][2];      // A slot p holds A(s), s&3==p; [2] = two M-tiles
    float4 wS[4];         // W slot p holds latest W(m), m&3==p

    // ---- prologue: A(0),A(1) and W(0..3) in flight; W(0),W(1) -> LDS
    aS[0][0] = *(const bf16x8*)(agp);
    aS[0][1] = *(const bf16x8*)(agp + 16 * HID);
    aS[1][0] = *(const bf16x8*)(agp + KC);
    aS[1][1] = *(const bf16x8*)(agp + KC + 16 * HID);
    wS[0] = *(const float4*)(sgp);
    wS[1] = *(const float4*)(sgp + 1 * KC);
    wS[2] = *(const float4*)(sgp + 2 * KC);
    wS[3] = *(const float4*)(sgp + 3 * KC);
    *(bf16x4*)(swr + 0 * BUFSZ) = cvt4(wS[0]);
    *(bf16x4*)(swr + 1 * BUFSZ) = cvt4(wS[1]);
    asm volatile("s_waitcnt lgkmcnt(0)" ::: "memory");
    __builtin_amdgcn_s_barrier();

    // step S (S&3 == P): issue A(S+2)->aS[(P+2)&3], W(S+4)->wS[P];
    // read buf P; MFMA with aS[P]; ds_write wS[(P+2)&3] (=W(S+2)) -> buf (P+2)&3
#define STEP(S, P, ISSA, ISSW, WRT, BAR)                                                    \
    {                                                                                       \
        if (ISSA) {                                                                         \
            aS[((P) + 2) & 3][0] = *(const bf16x8*)(agp + ((S) + 2) * KC);                  \
            aS[((P) + 2) & 3][1] = *(const bf16x8*)(agp + ((S) + 2) * KC + 16 * HID);       \
        }                                                                                   \
        if (ISSW) wS[(P)] = *(const float4*)(sgp + ((S) + 4) * KC);                         \
        __builtin_amdgcn_sched_barrier(0);                                                  \
        const char* rb = &wbuf[0] + (P) * BUFSZ;                                            \
        bf16x8 b0 = *(const bf16x8*)(rb + 0 * (16 * STRIDE) + boff);                        \
        bf16x8 b1 = *(const bf16x8*)(rb + 1 * (16 * STRIDE) + boff);                        \
        bf16x8 b2 = *(const bf16x8*)(rb + 2 * (16 * STRIDE) + boff);                        \
        bf16x8 b3 = *(const bf16x8*)(rb + 3 * (16 * STRIDE) + boff);                        \
        acc[0][0] = __builtin_amdgcn_mfma_f32_16x16x32_bf16(aS[P][0], b0, acc[0][0], 0, 0, 0); \
        acc[0][1] = __builtin_amdgcn_mfma_f32_16x16x32_bf16(aS[P][0], b1, acc[0][1], 0, 0, 0); \
        acc[0][2] = __builtin_amdgcn_mfma_f32_16x16x32_bf16(aS[P][0], b2, acc[0][2], 0, 0, 0); \
        acc[0][3] = __builtin_amdgcn_mfma_f32_16x16x32_bf16(aS[P][0], b3, acc[0][3], 0, 0, 0); \
        acc[1][0] = __builtin_amdgcn_mfma_f32_16x16x32_bf16(aS[P][1], b0, acc[1][0], 0, 0, 0); \
        acc[1][1] = __builtin_amdgcn_mfma_f32_16x16x32_bf16(aS[P][1], b1, acc[1][1], 0, 0, 0); \
        acc[1][2] = __builtin_amdgcn_mfma_f32_16x16x32_bf16(aS[P][1], b2, acc[1][2], 0, 0, 0); \
        acc[1][3] = __builtin_amdgcn_mfma_f32_16x16x32_bf16(aS[P][1], b3, acc[1][3], 0, 0, 0); \
        if (WRT) *(bf16x4*)(swr + (((P) + 2) & 3) * BUFSZ) = cvt4(wS[((P) + 2) & 3]);       \
        if (BAR) {                                                                          \
            asm volatile("s_waitcnt lgkmcnt(0)" ::: "memory");                              \
            __builtin_amdgcn_s_barrier();                                                   \
        }                                                                                   \
    }

    // main: 7 x 4 steps = s 0..27 (all issues in-bounds: A<=29+... A(s+2)<=31, W(s+4)<=31)
    for (int ii = 0; ii < 7; ++ii) {
        const int s = ii * 4;
        STEP(s + 0, 0, 1, 1, 1, 1)
        STEP(s + 1, 1, 1, 1, 1, 1)
        STEP(s + 2, 2, 1, 1, 1, 1)
        STEP(s + 3, 3, 1, 1, 1, 1)
    }
    // tail: 28,29 write W(30),W(31); 30,31 read-only (no barrier needed between)
    STEP(28, 0, 1, 0, 1, 1)
    STEP(29, 1, 1, 0, 1, 1)
    STEP(30, 2, 0, 0, 0, 0)
    STEP(31, 3, 0, 0, 0, 0)
#undef STEP

    // ---- epilogue: +b1, relu, *w2, shuffle-reduce over o (8 lanes), +b2, store
    const int col = lane & 15;
    const int rgrp = lane >> 4;
    const int o = col & 7;
#pragma unroll
    for (int nt = 0; nt < 4; ++nt) {
        const int tl = nt * 2 + (col >> 3);       // task-local 0..7
        const int task = tids[blk * TPB + tl];
        const float bb1 = b1[task * 8 + o];
        const float ww2 = W2[task * 8 + o];
#pragma unroll
        for (int bt = 0; bt < 2; ++bt) {
            float v[4];
#pragma unroll
            for (int r = 0; r < 4; ++r) {
                float x = acc[bt][nt][r] + bb1;
                x = x > 0.f ? x : 0.f;
                v[r] = x * ww2;
            }
#pragma unroll
            for (int m = 1; m <= 4; m <<= 1) {
#pragma unroll
                for (int r = 0; r < 4; ++r) v[r] += __shfl_xor(v[r], m, 64);
            }
            if ((lane & 7) == 0) {
                const float bb2 = b2[task];
                const int brow = w * 32 + bt * 16 + rgrp * 4;
                float4 o4 = make_float4(v[0] + bb2, v[1] + bb2, v[2] + bb2, v[3] + bb2);
                *(float4*)(out + (size_t)(blk * TPB + tl) * BATCH + brow) = o4;
            }
        }
    }
}

extern "C" void kernel_launch(void* const* d_in, const int* in_sizes, int n_in,
                              void* d_out, int out_size, void* d_ws, size_t ws_size,
                              hipStream_t stream) {
    const float* emb = (const float*)d_in[0];
    const float* W1  = (const float*)d_in[1];
    const float* b1  = (const float*)d_in[2];
    const float* W2  = (const float*)d_in[3];
    const float* b2  = (const float*)d_in[4];
    const int*   tid = (const int*)d_in[5];
    float* outp = (float*)d_out;
    __bf16* embb = (__bf16*)d_ws;   // 512 KB

    cvt_emb_kernel<<<dim3(BATCH * HID / (256 * 4)), dim3(256), 0, stream>>>(emb, embb);
    mtc_kernel<<<dim3(KTASK / TPB), dim3(512), 0, stream>>>(embb, W1, b1, W2, b2, tid, outp);
}